// Round 1
// 2851.921 us; speedup vs baseline: 1.0220x; 1.0220x over previous
//
#include <hip/hip_runtime.h>

// Spatial_MGCN on MI355X — round 3: bf16-mode big GEMMs moved to MFMA
// (v_mfma_f32_16x16x32_bf16, 128x128xBK64 tiles, pre-transposed B),
// dual-launched with the fp32 VALU fallback gated on the device dtype flag.
// CGCN branches in the reference are dead code and skipped.

typedef unsigned short bfu;   // raw bf16 bits
typedef __bf16 bf16x8 __attribute__((ext_vector_type(8)));
typedef float  f32x4  __attribute__((ext_vector_type(4)));

__device__ __forceinline__ float b2f(bfu u) {
    return __uint_as_float(((unsigned)u) << 16);
}
__device__ __forceinline__ bfu f2b(float f) {
    unsigned u = __float_as_uint(f);
    return (bfu)((u + 0x7FFFu + ((u >> 16) & 1u)) >> 16);   // RNE
}
__device__ __forceinline__ float ldm(const void* p, size_t i, int bf) {
    return bf ? b2f(((const bfu*)p)[i]) : ((const float*)p)[i];
}
__device__ __forceinline__ void stm(void* p, size_t i, float v, int bf) {
    if (bf) ((bfu*)p)[i] = f2b(v);
    else    ((float*)p)[i] = v;
}

// Detect input dtype from s_w (uniform[0,1)):
//  - bf16-packed: low ushort of each word is a bf16 < ~1.0 -> bits < 0x3F80
//  - fp32: low 16 bits are uniform mantissa -> ~25% are >= 0x3F80
__global__ void detect_dtype_k(const unsigned* __restrict__ sw, int* __restrict__ flag) {
    __shared__ int cnt;
    if (threadIdx.x == 0) cnt = 0;
    __syncthreads();
    unsigned w = sw[threadIdx.x];           // 256 words = 1 KB of s_w
    if ((w & 0xFFFFu) >= 0x3F80u) atomicAdd(&cnt, 1);
    __syncthreads();
    if (threadIdx.x == 0) *flag = (cnt < 25) ? 1 : 0;   // 1 = bf16 mode
}

enum { EPI_F32 = 0, EPI_SIG = 1, EPI_SP = 2 };

// ---------------------------------------------------------------------------
// bf16 tile transpose: out[C][R] = in[R][C].  Only runs in bf16 mode.
// ---------------------------------------------------------------------------
__global__ __launch_bounds__(256) void transpose_bf16_k(
    const bfu* __restrict__ in, bfu* __restrict__ out, int R, int C,
    const int* __restrict__ flag)
{
    if (!*flag) return;
    __shared__ bfu tile[64][66];    // 66 pitch -> conflict-free both ways
    int r0 = blockIdx.x * 64, c0 = blockIdx.y * 64;
    int tx = threadIdx.x & 63, ty = threadIdx.x >> 6;
    for (int i = ty; i < 64; i += 4) {
        int r = r0 + i, c = c0 + tx;
        tile[i][tx] = (r < R && c < C) ? in[(size_t)r * C + c] : (bfu)0;
    }
    __syncthreads();
    for (int i = ty; i < 64; i += 4) {
        int c = c0 + i, r = r0 + tx;
        if (c < C && r < R) out[(size_t)c * R + r] = tile[tx][i];
    }
}

// ---------------------------------------------------------------------------
// MFMA bf16 GEMM: C[M,Nn] = A[M,K] @ B[K,Nn], with Bt = B^T ([Nn][K]) input.
// 128x128 block tile, BK=64, 4 waves (2x2), each wave 64x64 out (4x4 frags of
// 16x16x32).  LDS rows padded to 72 bf16 (144 B) -> conflict-free b128 access.
// Only runs in bf16 mode; A and Bt are bf16, acc fp32.
// ---------------------------------------------------------------------------
template <int EPI>
__global__ __launch_bounds__(256) void gemm_mfma(
    const bfu* __restrict__ A, const bfu* __restrict__ Bt,
    const void* __restrict__ bias,
    float* __restrict__ Cf, void* __restrict__ Cb, size_t cb_off,
    int M, int K, int Nn, const int* __restrict__ flag)
{
    if (!*flag) return;
    __shared__ __align__(16) bfu As[128 * 72];
    __shared__ __align__(16) bfu Bs[128 * 72];

    const int t = threadIdx.x;
    const int bm0 = blockIdx.x * 128, bn0 = blockIdx.y * 128;
    const int lane = t & 63, wid = t >> 6;
    const int wm = (wid >> 1) * 64, wn = (wid & 1) * 64;
    const int lr = lane & 15;            // fragment row/col
    const int lk = (lane >> 4) * 8;      // fragment k offset
    const int lq = (lane >> 4) * 4;      // C/D row offset

    f32x4 acc[4][4] = {};

    // staging: per thread 4 chunks of 8 bf16 per matrix per BK-step
    const int srow = t >> 3;             // 0..31
    const int skoff = (t & 7) * 8;       // 0..56

    for (int k0 = 0; k0 < K; k0 += 64) {
        int4 va[4], vb[4];
        #pragma unroll
        for (int h = 0; h < 4; h++) {
            int row = srow + h * 32;
            int gk = k0 + skoff;
            va[h] = make_int4(0, 0, 0, 0);
            vb[h] = make_int4(0, 0, 0, 0);
            int gm = bm0 + row;
            if (gm < M && gk < K)
                va[h] = *(const int4*)(A + (size_t)gm * K + gk);
            int gn = bn0 + row;
            if (gn < Nn && gk < K)
                vb[h] = *(const int4*)(Bt + (size_t)gn * K + gk);
        }
        __syncthreads();                 // previous iter's reads done
        #pragma unroll
        for (int h = 0; h < 4; h++) {
            int row = srow + h * 32;
            *(int4*)&As[row * 72 + skoff] = va[h];
            *(int4*)&Bs[row * 72 + skoff] = vb[h];
        }
        __syncthreads();                 // writes visible

        #pragma unroll
        for (int kk = 0; kk < 2; kk++) {
            bf16x8 af[4], bq[4];
            #pragma unroll
            for (int i = 0; i < 4; i++) {
                af[i] = *(const bf16x8*)&As[(wm + i * 16 + lr) * 72 + kk * 32 + lk];
                bq[i] = *(const bf16x8*)&Bs[(wn + i * 16 + lr) * 72 + kk * 32 + lk];
            }
            #pragma unroll
            for (int i = 0; i < 4; i++)
                #pragma unroll
                for (int j = 0; j < 4; j++)
                    acc[i][j] = __builtin_amdgcn_mfma_f32_16x16x32_bf16(
                        af[i], bq[j], acc[i][j], 0, 0, 0);
        }
    }

    // epilogue: C/D layout col = lane&15, row = (lane>>4)*4 + r
    #pragma unroll
    for (int j = 0; j < 4; j++) {
        int col = bn0 + wn + j * 16 + lr;
        if (col >= Nn) continue;
        #pragma unroll
        for (int i = 0; i < 4; i++) {
            #pragma unroll
            for (int r = 0; r < 4; r++) {
                int row = bm0 + wm + i * 16 + lq + r;
                if (row >= M) continue;
                float v = acc[i][j][r];
                if constexpr (EPI == EPI_F32) {
                    Cf[(size_t)row * Nn + col] = v;
                } else if constexpr (EPI == EPI_SIG) {
                    v += ldm(bias, col, 1);
                    v = 1.f / (1.f + __expf(-v));
                    stm(Cb, cb_off + (size_t)row * Nn + col, v, 1);
                } else {   // EPI_SP: softplus + clip(1e-4, 1e4)
                    v += ldm(bias, col, 1);
                    float sp = (v > 20.f) ? v : log1pf(__expf(v));
                    sp = fminf(fmaxf(sp, 1e-4f), 1e4f);
                    stm(Cb, cb_off + (size_t)row * Nn + col, sp, 1);
                }
            }
        }
    }
}

// ---------------------------------------------------------------------------
// Tiled VALU GEMM (fallback / small GEMMs).  FP32ONLY gates the big GEMMs off
// in bf16 mode (the MFMA kernel handles those).
// ---------------------------------------------------------------------------
template <bool AGLB, int EPI, bool FP32ONLY>
__global__ __launch_bounds__(256) void gemm_tiled(
    const void* __restrict__ A, const void* __restrict__ B,
    const void* __restrict__ bias,
    float* __restrict__ Cf, void* __restrict__ Cb, size_t cb_off,
    int M, int K, int Nn, const int* __restrict__ flag)
{
    __shared__ __align__(16) float As[16][68];
    __shared__ __align__(16) float Bs[16][68];

    const int bf = *flag;
    if (FP32ONLY && bf) return;          // uniform branch, barrier-safe
    const int t = threadIdx.x;
    const int bm0 = blockIdx.x * 64, bn0 = blockIdx.y * 64;
    const int tx = t & 15, ty = t >> 4;

    const int am = t >> 2;
    const int ak = (t & 3) * 4;
    const int gm = bm0 + am;
    const bool arow = gm < M;
    const int bk = t >> 4;
    const int bn = (t & 15) * 4;
    const bool bcol = (bn0 + bn + 3) < Nn;

    float acc[4][4] = {};

    for (int k0 = 0; k0 < K; k0 += 16) {
        float av0 = 0.f, av1 = 0.f, av2 = 0.f, av3 = 0.f;
        float bv0 = 0.f, bv1 = 0.f, bv2 = 0.f, bv3 = 0.f;
        if (arow) {
            size_t off = (size_t)gm * K + k0 + ak;
            if (AGLB && bf) {
                ushort4 v = *(const ushort4*)((const bfu*)A + off);
                av0 = b2f(v.x); av1 = b2f(v.y); av2 = b2f(v.z); av3 = b2f(v.w);
            } else {
                float4 v = *(const float4*)((const float*)A + off);
                av0 = v.x; av1 = v.y; av2 = v.z; av3 = v.w;
            }
        }
        if (bcol) {
            size_t off = (size_t)(k0 + bk) * Nn + bn0 + bn;
            if (bf) {
                ushort4 v = *(const ushort4*)((const bfu*)B + off);
                bv0 = b2f(v.x); bv1 = b2f(v.y); bv2 = b2f(v.z); bv3 = b2f(v.w);
            } else {
                float4 v = *(const float4*)((const float*)B + off);
                bv0 = v.x; bv1 = v.y; bv2 = v.z; bv3 = v.w;
            }
        }

        __syncthreads();
        As[ak + 0][am] = av0; As[ak + 1][am] = av1;
        As[ak + 2][am] = av2; As[ak + 3][am] = av3;
        *(float4*)&Bs[bk][bn] = make_float4(bv0, bv1, bv2, bv3);
        __syncthreads();

        #pragma unroll
        for (int k = 0; k < 16; k++) {
            float4 a4 = *(const float4*)&As[k][ty * 4];
            float4 b4 = *(const float4*)&Bs[k][tx * 4];
            float aa[4] = {a4.x, a4.y, a4.z, a4.w};
            float bb[4] = {b4.x, b4.y, b4.z, b4.w};
            #pragma unroll
            for (int i = 0; i < 4; i++)
                #pragma unroll
                for (int j = 0; j < 4; j++)
                    acc[i][j] += aa[i] * bb[j];
        }
    }

    #pragma unroll
    for (int i = 0; i < 4; i++) {
        int row = bm0 + ty * 4 + i;
        if (row >= M) continue;
        #pragma unroll
        for (int j = 0; j < 4; j++) {
            int col = bn0 + tx * 4 + j;
            if (col >= Nn) continue;
            float v = acc[i][j];
            if constexpr (EPI == EPI_F32) {
                Cf[(size_t)row * Nn + col] = v;
            } else if constexpr (EPI == EPI_SIG) {
                v += ldm(bias, col, bf);
                v = 1.f / (1.f + __expf(-v));
                stm(Cb, cb_off + (size_t)row * Nn + col, v, bf);
            } else {
                v += ldm(bias, col, bf);
                float sp = (v > 20.f) ? v : log1pf(__expf(v));
                sp = fminf(fmaxf(sp, 1e-4f), 1e4f);
                stm(Cb, cb_off + (size_t)row * Nn + col, sp, bf);
            }
        }
    }
}

// out[dst] += w * Hin[src]  (one wave per edge; lanes stride columns)
__global__ __launch_bounds__(256) void spmm_scatter(
    const float* __restrict__ Hin, const int* __restrict__ src,
    const int* __restrict__ dst, const void* __restrict__ w,
    float* __restrict__ outp, int E, int C, const int* __restrict__ flag)
{
    int bf = *flag;
    int gw = (blockIdx.x * 256 + threadIdx.x) >> 6;
    int lane = threadIdx.x & 63;
    if (gw >= E) return;
    int s = src[gw], d = dst[gw];
    float ww = ldm(w, gw, bf);
    const float* hp = Hin + (size_t)s * C;
    float* op = outp + (size_t)d * C;
    for (int c = lane; c < C; c += 64)
        atomicAdd(&op[c], ww * hp[c]);
}

// H = relu(H + bias[c]),  C power of two
__global__ __launch_bounds__(256) void bias_relu_k(
    float* __restrict__ H, const void* __restrict__ bias, int total, int Cm1,
    const int* __restrict__ flag)
{
    int bf = *flag;
    int i = blockIdx.x * 256 + threadIdx.x;
    if (i >= total) return;
    float v = H[i] + ldm(bias, i & Cm1, bf);
    H[i] = fmaxf(v, 0.f);
}

// E += bias[c] (C=64); keep fp32 copy, also emit output at out_off
__global__ __launch_bounds__(256) void bias_store_emb_k(
    float* __restrict__ Ef, const void* __restrict__ bias,
    void* __restrict__ outb, size_t out_off, int total,
    const int* __restrict__ flag)
{
    int bf = *flag;
    int i = blockIdx.x * 256 + threadIdx.x;
    if (i >= total) return;
    float v = Ef[i] + ldm(bias, i & 63, bf);
    Ef[i] = v;
    stm(outb, out_off + i, v, bf);
}

// BatchNorm1d (eval) + bias + relu on [N,256] fp32, in-place.
// In bf16 mode also emits a bf16 copy (MFMA decoder A operand).
__global__ __launch_bounds__(256) void bn_relu_k(
    float* __restrict__ H, const void* __restrict__ bd,
    const void* __restrict__ g, const void* __restrict__ b,
    const void* __restrict__ rm, const void* __restrict__ rv,
    bfu* __restrict__ hb, int total, const int* __restrict__ flag)
{
    int bf = *flag;
    int i = blockIdx.x * 256 + threadIdx.x;
    if (i >= total) return;
    int c = i & 255;
    float v = H[i] + ldm(bd, c, bf);
    v = (v - ldm(rm, c, bf)) * rsqrtf(ldm(rv, c, bf) + 1e-5f) * ldm(g, c, bf)
        + ldm(b, c, bf);
    v = fmaxf(v, 0.f);
    H[i] = v;
    if (bf) hb[i] = f2b(v);
}

// Per-node: attention over {emb1, emb2} + Wm MLP. One wave per node, 4/block.
__global__ __launch_bounds__(256) void attn_mlp_k(
    const float* __restrict__ E1, const float* __restrict__ E2,
    const void* __restrict__ Wa1, const void* __restrict__ ba1,
    const void* __restrict__ Wa2,
    const void* __restrict__ Wm, const void* __restrict__ bm,
    float* __restrict__ Eout, void* __restrict__ outb, size_t out_off,
    const int* __restrict__ flag)
{
    __shared__ float sh[4][3][64];   // per-wave: e1, e2, comb
    int bf = *flag;
    int wid = threadIdx.x >> 6, lane = threadIdx.x & 63;
    int node = blockIdx.x * 4 + wid;             // grid*4 == N exactly

    float e1 = E1[(size_t)node * 64 + lane];
    float e2 = E2[(size_t)node * 64 + lane];
    sh[wid][0][lane] = e1;
    sh[wid][1][lane] = e2;
    __syncthreads();

    float part = 0.f;
    if (lane < 32) {                 // lanes 0..15: logit1 partials, 16..31: logit2
        int tt = lane & 15;
        const float* es = sh[wid][lane >> 4];
        float a = 0.f;
        for (int m = 0; m < 64; m++) a += es[m] * ldm(Wa1, m * 16 + tt, bf);
        part = tanhf(a + ldm(ba1, tt, bf)) * ldm(Wa2, tt, bf);
    }
    part += __shfl_xor(part, 1);
    part += __shfl_xor(part, 2);
    part += __shfl_xor(part, 4);
    part += __shfl_xor(part, 8);
    float lg1 = __shfl(part, 0);
    float lg2 = __shfl(part, 16);
    float mx = fmaxf(lg1, lg2);
    float p1 = __expf(lg1 - mx), p2 = __expf(lg2 - mx);
    float inv = 1.f / (p1 + p2);
    float comb = (p1 * inv) * e1 + (p2 * inv) * e2;
    sh[wid][2][lane] = comb;
    __syncthreads();

    const float* cs = sh[wid][2];
    float acc = ldm(bm, lane, bf);
    for (int m = 0; m < 64; m++) acc += cs[m] * ldm(Wm, m * 64 + lane, bf);
    size_t idx = (size_t)node * 64 + lane;
    Eout[idx] = acc;
    stm(outb, out_off + idx, acc, bf);
}

extern "C" void kernel_launch(void* const* d_in, const int* in_sizes, int n_in,
                              void* d_out, int out_size, void* d_ws, size_t ws_size,
                              hipStream_t stream)
{
    const int N = 20000, F = 2000, H1 = 256, H2 = 64, E = 320000, FOUT = 2000;

    const void* x     = d_in[0];
    const int* s_src = (const int*)d_in[1];
    const int* s_dst = (const int*)d_in[2];
    const void* s_w   = d_in[3];
    const int* f_src = (const int*)d_in[4];
    const int* f_dst = (const int*)d_in[5];
    const void* f_w   = d_in[6];
    const void *Ws1 = d_in[7],  *bs1 = d_in[8];
    const void *Ws2 = d_in[9],  *bs2 = d_in[10];
    const void *Wf1 = d_in[11], *bf1 = d_in[12];
    const void *Wf2 = d_in[13], *bf2 = d_in[14];
    // d_in[15..18] = Wc1,bc1,Wc2,bc2 -> dead code in reference, skipped
    const void *Wa1 = d_in[19], *ba1 = d_in[20];
    const void *Wa2 = d_in[21];
    const void *Wm  = d_in[22], *bm  = d_in[23];
    const void *Wd  = d_in[24], *bd  = d_in[25];
    const void *bn_g = d_in[26], *bn_b = d_in[27];
    const void *bn_rm = d_in[28], *bn_rv = d_in[29];
    const void *Wpi = d_in[30], *bpi = d_in[31];
    const void *Wdp = d_in[32], *bdp = d_in[33];
    const void *Wmu = d_in[34], *bmu = d_in[35];

    // output element offsets (dtype-agnostic)
    const size_t o_emb1 = 0;
    const size_t o_emb2 = (size_t)N * H2;
    const size_t o_emb  = 2 * (size_t)N * H2;
    const size_t o_pi   = 3 * (size_t)N * H2;
    const size_t o_disp = o_pi + (size_t)N * FOUT;
    const size_t o_mean = o_disp + (size_t)N * FOUT;

    // workspace: [flag:256B][XW N*256][H N*256][G2 N*64][e1f N*64][e2f N*64][emf N*64]
    char* wsb = (char*)d_ws;
    int* flag = (int*)wsb;
    float* XW  = (float*)(wsb + 256);
    float* H   = XW + (size_t)N * H1;
    float* G2  = H  + (size_t)N * H1;
    float* e1f = G2 + (size_t)N * H2;
    float* e2f = e1f + (size_t)N * H2;
    float* emf = e2f + (size_t)N * H2;
    float* hdec = XW;              // reuse: XW dead after f-path spmm layer 1
    // bf16-mode aliases over dead fp32 regions (stream-ordered, no overlap live):
    bfu* hdec_bf = (bfu*)H;        // decoder phase: H dead (needs N*H1*2 = 10.2 MB)
    bfu* Bt      = (bfu*)G2;       // transposed weight staging (needs 1.0 MB)

    const int MB  = (N + 63) / 64;     // 313
    const int MB2 = (N + 127) / 128;   // 157

    detect_dtype_k<<<1, 256, 0, stream>>>((const unsigned*)s_w, flag);

    // ---- s-graph GCN ----
    transpose_bf16_k<<<dim3(32, 4), 256, 0, stream>>>(
        (const bfu*)Ws1, Bt, F, H1, flag);
    gemm_mfma<EPI_F32><<<dim3(MB2, 2), 256, 0, stream>>>(
        (const bfu*)x, Bt, nullptr, XW, nullptr, 0, N, F, H1, flag);
    gemm_tiled<true, EPI_F32, true><<<dim3(MB, 4), 256, 0, stream>>>(
        x, Ws1, nullptr, XW, nullptr, 0, N, F, H1, flag);
    hipMemsetAsync(H, 0, (size_t)N * H1 * 4, stream);
    spmm_scatter<<<E / 4, 256, 0, stream>>>(XW, s_src, s_dst, s_w, H, E, H1, flag);
    bias_relu_k<<<(N * H1) / 256, 256, 0, stream>>>(H, bs1, N * H1, H1 - 1, flag);
    gemm_tiled<false, EPI_F32, false><<<dim3(MB, 1), 256, 0, stream>>>(
        H, Ws2, nullptr, G2, nullptr, 0, N, H1, H2, flag);
    hipMemsetAsync(e1f, 0, (size_t)N * H2 * 4, stream);
    spmm_scatter<<<E / 4, 256, 0, stream>>>(G2, s_src, s_dst, s_w, e1f, E, H2, flag);
    bias_store_emb_k<<<(N * H2) / 256, 256, 0, stream>>>(
        e1f, bs2, d_out, o_emb1, N * H2, flag);

    // ---- f-graph GCN (reuses XW, H, G2) ----
    transpose_bf16_k<<<dim3(32, 4), 256, 0, stream>>>(
        (const bfu*)Wf1, Bt, F, H1, flag);
    gemm_mfma<EPI_F32><<<dim3(MB2, 2), 256, 0, stream>>>(
        (const bfu*)x, Bt, nullptr, XW, nullptr, 0, N, F, H1, flag);
    gemm_tiled<true, EPI_F32, true><<<dim3(MB, 4), 256, 0, stream>>>(
        x, Wf1, nullptr, XW, nullptr, 0, N, F, H1, flag);
    hipMemsetAsync(H, 0, (size_t)N * H1 * 4, stream);
    spmm_scatter<<<E / 4, 256, 0, stream>>>(XW, f_src, f_dst, f_w, H, E, H1, flag);
    bias_relu_k<<<(N * H1) / 256, 256, 0, stream>>>(H, bf1, N * H1, H1 - 1, flag);
    gemm_tiled<false, EPI_F32, false><<<dim3(MB, 1), 256, 0, stream>>>(
        H, Wf2, nullptr, G2, nullptr, 0, N, H1, H2, flag);
    hipMemsetAsync(e2f, 0, (size_t)N * H2 * 4, stream);
    spmm_scatter<<<E / 4, 256, 0, stream>>>(G2, f_src, f_dst, f_w, e2f, E, H2, flag);
    bias_store_emb_k<<<(N * H2) / 256, 256, 0, stream>>>(
        e2f, bf2, d_out, o_emb2, N * H2, flag);

    // ---- attention + Wm ----
    attn_mlp_k<<<N / 4, 256, 0, stream>>>(
        e1f, e2f, Wa1, ba1, Wa2, Wm, bm, emf, d_out, o_emb, flag);

    // ---- decoder ----
    gemm_tiled<false, EPI_F32, false><<<dim3(MB, 4), 256, 0, stream>>>(
        emf, Wd, nullptr, hdec, nullptr, 0, N, H2, H1, flag);
    bn_relu_k<<<(N * H1) / 256, 256, 0, stream>>>(
        hdec, bd, bn_g, bn_b, bn_rm, bn_rv, hdec_bf, N * H1, flag);

    // pi
    transpose_bf16_k<<<dim3(4, 32), 256, 0, stream>>>(
        (const bfu*)Wpi, Bt, H1, FOUT, flag);
    gemm_mfma<EPI_SIG><<<dim3(MB2, 16), 256, 0, stream>>>(
        hdec_bf, Bt, bpi, nullptr, d_out, o_pi, N, H1, FOUT, flag);
    gemm_tiled<false, EPI_SIG, true><<<dim3(MB, 32), 256, 0, stream>>>(
        hdec, Wpi, bpi, nullptr, d_out, o_pi, N, H1, FOUT, flag);
    // disp
    transpose_bf16_k<<<dim3(4, 32), 256, 0, stream>>>(
        (const bfu*)Wdp, Bt, H1, FOUT, flag);
    gemm_mfma<EPI_SP><<<dim3(MB2, 16), 256, 0, stream>>>(
        hdec_bf, Bt, bdp, nullptr, d_out, o_disp, N, H1, FOUT, flag);
    gemm_tiled<false, EPI_SP, true><<<dim3(MB, 32), 256, 0, stream>>>(
        hdec, Wdp, bdp, nullptr, d_out, o_disp, N, H1, FOUT, flag);
    // mean
    transpose_bf16_k<<<dim3(4, 32), 256, 0, stream>>>(
        (const bfu*)Wmu, Bt, H1, FOUT, flag);
    gemm_mfma<EPI_SIG><<<dim3(MB2, 16), 256, 0, stream>>>(
        hdec_bf, Bt, bmu, nullptr, d_out, o_mean, N, H1, FOUT, flag);
    gemm_tiled<false, EPI_SIG, true><<<dim3(MB, 32), 256, 0, stream>>>(
        hdec, Wmu, bmu, nullptr, d_out, o_mean, N, H1, FOUT, flag);
}

// Round 2
// 2494.676 us; speedup vs baseline: 1.1684x; 1.1432x over previous
//
#include <hip/hip_runtime.h>

// Spatial_MGCN on MI355X — round 4.
// Key finding from round-3 counters: the data is FP32 (WRITE_SIZE of decoder
// GEMMs = 167 MB = fp32 stores; in_npz = 165 MB = fp32 x).  The bf16 MFMA
// path never ran.  This round: split-fp32 (bf16x3) MFMA GEMM for the 5 big
// GEMMs in fp32 mode: a = a_hi + a_lo (bf16 each), C += Ah*Bh + Ah*Bl + Al*Bh
// on v_mfma_f32_16x16x32_bf16 with fp32 accumulation (~16-bit mantissa,
// rel err ~1e-4 << the 0.125 reference deviation band).
// CGCN branches in the reference are dead code and skipped.

typedef unsigned short bfu;   // raw bf16 bits
typedef __bf16 bf16x8 __attribute__((ext_vector_type(8)));
typedef float  f32x4  __attribute__((ext_vector_type(4)));

__device__ __forceinline__ float b2f(bfu u) {
    return __uint_as_float(((unsigned)u) << 16);
}
__device__ __forceinline__ bfu f2b(float f) {
    unsigned u = __float_as_uint(f);
    return (bfu)((u + 0x7FFFu + ((u >> 16) & 1u)) >> 16);   // RNE
}
__device__ __forceinline__ float ldm(const void* p, size_t i, int bf) {
    return bf ? b2f(((const bfu*)p)[i]) : ((const float*)p)[i];
}
__device__ __forceinline__ void stm(void* p, size_t i, float v, int bf) {
    if (bf) ((bfu*)p)[i] = f2b(v);
    else    ((float*)p)[i] = v;
}
// truncation split: f = b2f(h) + ~lo, |dropped lo*lo| ~ 2^-16 rel
__device__ __forceinline__ void splitf(float f, bfu& h, bfu& l) {
    unsigned u = __float_as_uint(f);
    h = (bfu)(u >> 16);
    float r = f - __uint_as_float(u & 0xFFFF0000u);
    l = f2b(r);
}

// Detect input dtype from s_w (uniform[0,1)):
//  - bf16-packed: low ushort of each word is a bf16 < ~1.0 -> bits < 0x3F80
//  - fp32: low 16 bits are uniform mantissa -> ~75% are >= 0x3F80
__global__ void detect_dtype_k(const unsigned* __restrict__ sw, int* __restrict__ flag) {
    __shared__ int cnt;
    if (threadIdx.x == 0) cnt = 0;
    __syncthreads();
    unsigned w = sw[threadIdx.x];           // 256 words = 1 KB of s_w
    if ((w & 0xFFFFu) >= 0x3F80u) atomicAdd(&cnt, 1);
    __syncthreads();
    if (threadIdx.x == 0) *flag = (cnt < 25) ? 1 : 0;   // 1 = bf16 mode
}

enum { EPI_F32 = 0, EPI_SIG = 1, EPI_SP = 2 };

// ---------------------------------------------------------------------------
// bf16 tile transpose: out[C][R] = in[R][C].  Only runs in bf16 mode.
// ---------------------------------------------------------------------------
__global__ __launch_bounds__(256) void transpose_bf16_k(
    const bfu* __restrict__ in, bfu* __restrict__ out, int R, int C,
    const int* __restrict__ flag)
{
    if (!*flag) return;
    __shared__ bfu tile[64][66];
    int r0 = blockIdx.x * 64, c0 = blockIdx.y * 64;
    int tx = threadIdx.x & 63, ty = threadIdx.x >> 6;
    for (int i = ty; i < 64; i += 4) {
        int r = r0 + i, c = c0 + tx;
        tile[i][tx] = (r < R && c < C) ? in[(size_t)r * C + c] : (bfu)0;
    }
    __syncthreads();
    for (int i = ty; i < 64; i += 4) {
        int c = c0 + i, r = r0 + tx;
        if (c < C && r < R) out[(size_t)c * R + r] = tile[tx][i];
    }
}

// ---------------------------------------------------------------------------
// fp32 transpose + split: in[R][C] fp32 -> ohi[C][R], olo[C][R] bf16.
// Only runs in fp32 mode.
// ---------------------------------------------------------------------------
__global__ __launch_bounds__(256) void transpose_split_f32_k(
    const float* __restrict__ in, bfu* __restrict__ ohi, bfu* __restrict__ olo,
    int R, int C, const int* __restrict__ flag)
{
    if (*flag) return;
    __shared__ float tile[64][65];
    int r0 = blockIdx.x * 64, c0 = blockIdx.y * 64;
    int tx = threadIdx.x & 63, ty = threadIdx.x >> 6;
    for (int i = ty; i < 64; i += 4) {
        int r = r0 + i, c = c0 + tx;
        tile[i][tx] = (r < R && c < C) ? in[(size_t)r * C + c] : 0.f;
    }
    __syncthreads();
    for (int i = ty; i < 64; i += 4) {
        int c = c0 + i, r = r0 + tx;
        if (c < C && r < R) {
            float v = tile[tx][i];
            bfu h, l; splitf(v, h, l);
            ohi[(size_t)c * R + r] = h;
            olo[(size_t)c * R + r] = l;
        }
    }
}

// ---------------------------------------------------------------------------
// MFMA bf16 GEMM (bf16-mode inputs): C = A @ B with Bt = B^T.  128x128xBK64.
// ---------------------------------------------------------------------------
template <int EPI>
__global__ __launch_bounds__(256) void gemm_mfma(
    const bfu* __restrict__ A, const bfu* __restrict__ Bt,
    const void* __restrict__ bias,
    float* __restrict__ Cf, void* __restrict__ Cb, size_t cb_off,
    int M, int K, int Nn, const int* __restrict__ flag)
{
    if (!*flag) return;
    __shared__ __align__(16) bfu As[128 * 72];
    __shared__ __align__(16) bfu Bs[128 * 72];

    const int t = threadIdx.x;
    const int bm0 = blockIdx.x * 128, bn0 = blockIdx.y * 128;
    const int lane = t & 63, wid = t >> 6;
    const int wm = (wid >> 1) * 64, wn = (wid & 1) * 64;
    const int lr = lane & 15;
    const int lk = (lane >> 4) * 8;
    const int lq = (lane >> 4) * 4;

    f32x4 acc[4][4] = {};

    const int srow = t >> 3;             // 0..31
    const int skoff = (t & 7) * 8;       // 0..56

    for (int k0 = 0; k0 < K; k0 += 64) {
        int4 va[4], vb[4];
        #pragma unroll
        for (int h = 0; h < 4; h++) {
            int row = srow + h * 32;
            int gk = k0 + skoff;
            va[h] = make_int4(0, 0, 0, 0);
            vb[h] = make_int4(0, 0, 0, 0);
            int gm = bm0 + row;
            if (gm < M && gk < K)
                va[h] = *(const int4*)(A + (size_t)gm * K + gk);
            int gn = bn0 + row;
            if (gn < Nn && gk < K)
                vb[h] = *(const int4*)(Bt + (size_t)gn * K + gk);
        }
        __syncthreads();
        #pragma unroll
        for (int h = 0; h < 4; h++) {
            int row = srow + h * 32;
            *(int4*)&As[row * 72 + skoff] = va[h];
            *(int4*)&Bs[row * 72 + skoff] = vb[h];
        }
        __syncthreads();

        #pragma unroll
        for (int kk = 0; kk < 2; kk++) {
            bf16x8 af[4], bq[4];
            #pragma unroll
            for (int i = 0; i < 4; i++) {
                af[i] = *(const bf16x8*)&As[(wm + i * 16 + lr) * 72 + kk * 32 + lk];
                bq[i] = *(const bf16x8*)&Bs[(wn + i * 16 + lr) * 72 + kk * 32 + lk];
            }
            #pragma unroll
            for (int i = 0; i < 4; i++)
                #pragma unroll
                for (int j = 0; j < 4; j++)
                    acc[i][j] = __builtin_amdgcn_mfma_f32_16x16x32_bf16(
                        af[i], bq[j], acc[i][j], 0, 0, 0);
        }
    }

    #pragma unroll
    for (int j = 0; j < 4; j++) {
        int col = bn0 + wn + j * 16 + lr;
        if (col >= Nn) continue;
        #pragma unroll
        for (int i = 0; i < 4; i++) {
            #pragma unroll
            for (int r = 0; r < 4; r++) {
                int row = bm0 + wm + i * 16 + lq + r;
                if (row >= M) continue;
                float v = acc[i][j][r];
                if constexpr (EPI == EPI_F32) {
                    Cf[(size_t)row * Nn + col] = v;
                } else if constexpr (EPI == EPI_SIG) {
                    v += ldm(bias, col, 1);
                    v = 1.f / (1.f + __expf(-v));
                    stm(Cb, cb_off + (size_t)row * Nn + col, v, 1);
                } else {
                    v += ldm(bias, col, 1);
                    float sp = (v > 20.f) ? v : log1pf(__expf(v));
                    sp = fminf(fmaxf(sp, 1e-4f), 1e4f);
                    stm(Cb, cb_off + (size_t)row * Nn + col, sp, 1);
                }
            }
        }
    }
}

// ---------------------------------------------------------------------------
// Split-fp32 MFMA GEMM (fp32 mode): C = A @ B, Bt pre-split (Bth/Btl, [Nn][K]).
// APRE=false: A is fp32 [M][K], split on the fly during staging.
// APRE=true:  A pre-split as Ah/Al bf16 [M][K] (decoder path).
// acc += Ah*Bh + Ah*Bl + Al*Bh  (3 MFMA per fragment pair, fp32 accumulate).
// 128x128 tile, BK=64, 4 waves (2x2), 72 KB LDS -> 2 blocks/CU.
// ---------------------------------------------------------------------------
template <int EPI, bool APRE>
__global__ __launch_bounds__(256, 2) void gemm_mfma_split(
    const float* __restrict__ Af,
    const bfu* __restrict__ Ah, const bfu* __restrict__ Al,
    const bfu* __restrict__ Bth, const bfu* __restrict__ Btl,
    const float* __restrict__ bias,
    float* __restrict__ Cf, float* __restrict__ Cb, size_t cb_off,
    int M, int K, int Nn, const int* __restrict__ flag)
{
    if (*flag) return;   // fp32 mode only
    __shared__ __align__(16) bfu Ash[128 * 72];
    __shared__ __align__(16) bfu Asl[128 * 72];
    __shared__ __align__(16) bfu Bsh[128 * 72];
    __shared__ __align__(16) bfu Bsl[128 * 72];

    const int t = threadIdx.x;
    const int bm0 = blockIdx.x * 128, bn0 = blockIdx.y * 128;
    const int lane = t & 63, wid = t >> 6;
    const int wm = (wid >> 1) * 64, wn = (wid & 1) * 64;
    const int lr = lane & 15;
    const int lk = (lane >> 4) * 8;
    const int lq = (lane >> 4) * 4;

    f32x4 acc[4][4] = {};

    const int srow = t >> 1;            // 0..127
    const int scol = (t & 1) * 32;      // 0 or 32
    const int gm = bm0 + srow;
    const int gn = bn0 + srow;
    const bool amok = gm < M;
    const bool bnok = gn < Nn;

    for (int k0 = 0; k0 < K; k0 += 64) {
        float4 va[8];                   // !APRE: 32 fp32 of A
        int4 vah[4], val[4];            //  APRE: 32 bf16 hi + lo of A
        int4 vbh[4], vbl[4];
        if constexpr (!APRE) {
            #pragma unroll
            for (int c = 0; c < 8; c++) {
                int gk = k0 + scol + c * 4;
                va[c] = make_float4(0.f, 0.f, 0.f, 0.f);
                if (amok && gk < K)
                    va[c] = *(const float4*)(Af + (size_t)gm * K + gk);
            }
        } else {
            #pragma unroll
            for (int c = 0; c < 4; c++) {
                int gk = k0 + scol + c * 8;
                vah[c] = make_int4(0, 0, 0, 0);
                val[c] = make_int4(0, 0, 0, 0);
                if (amok && gk < K) {
                    vah[c] = *(const int4*)(Ah + (size_t)gm * K + gk);
                    val[c] = *(const int4*)(Al + (size_t)gm * K + gk);
                }
            }
        }
        #pragma unroll
        for (int c = 0; c < 4; c++) {
            int gk = k0 + scol + c * 8;
            vbh[c] = make_int4(0, 0, 0, 0);
            vbl[c] = make_int4(0, 0, 0, 0);
            if (bnok && gk < K) {
                vbh[c] = *(const int4*)(Bth + (size_t)gn * K + gk);
                vbl[c] = *(const int4*)(Btl + (size_t)gn * K + gk);
            }
        }

        __syncthreads();                 // previous iter's LDS reads done
        if constexpr (!APRE) {
            #pragma unroll
            for (int c = 0; c < 8; c++) {
                ushort4 hv, lv;
                splitf(va[c].x, hv.x, lv.x);
                splitf(va[c].y, hv.y, lv.y);
                splitf(va[c].z, hv.z, lv.z);
                splitf(va[c].w, hv.w, lv.w);
                *(ushort4*)&Ash[srow * 72 + scol + c * 4] = hv;
                *(ushort4*)&Asl[srow * 72 + scol + c * 4] = lv;
            }
        } else {
            #pragma unroll
            for (int c = 0; c < 4; c++) {
                *(int4*)&Ash[srow * 72 + scol + c * 8] = vah[c];
                *(int4*)&Asl[srow * 72 + scol + c * 8] = val[c];
            }
        }
        #pragma unroll
        for (int c = 0; c < 4; c++) {
            *(int4*)&Bsh[srow * 72 + scol + c * 8] = vbh[c];
            *(int4*)&Bsl[srow * 72 + scol + c * 8] = vbl[c];
        }
        __syncthreads();                 // writes visible

        #pragma unroll
        for (int kk = 0; kk < 2; kk++) {
            bf16x8 ah[4], al4[4], bh[4], bl4[4];
            #pragma unroll
            for (int i = 0; i < 4; i++) {
                int ao = (wm + i * 16 + lr) * 72 + kk * 32 + lk;
                int bo = (wn + i * 16 + lr) * 72 + kk * 32 + lk;
                ah[i]  = *(const bf16x8*)&Ash[ao];
                al4[i] = *(const bf16x8*)&Asl[ao];
                bh[i]  = *(const bf16x8*)&Bsh[bo];
                bl4[i] = *(const bf16x8*)&Bsl[bo];
            }
            #pragma unroll
            for (int i = 0; i < 4; i++)
                #pragma unroll
                for (int j = 0; j < 4; j++) {
                    acc[i][j] = __builtin_amdgcn_mfma_f32_16x16x32_bf16(
                        ah[i], bh[j], acc[i][j], 0, 0, 0);
                    acc[i][j] = __builtin_amdgcn_mfma_f32_16x16x32_bf16(
                        ah[i], bl4[j], acc[i][j], 0, 0, 0);
                    acc[i][j] = __builtin_amdgcn_mfma_f32_16x16x32_bf16(
                        al4[i], bh[j], acc[i][j], 0, 0, 0);
                }
        }
    }

    // epilogue: C/D layout col = lane&15, row = (lane>>4)*4 + r  (fp32 I/O)
    #pragma unroll
    for (int j = 0; j < 4; j++) {
        int col = bn0 + wn + j * 16 + lr;
        if (col >= Nn) continue;
        #pragma unroll
        for (int i = 0; i < 4; i++) {
            #pragma unroll
            for (int r = 0; r < 4; r++) {
                int row = bm0 + wm + i * 16 + lq + r;
                if (row >= M) continue;
                float v = acc[i][j][r];
                if constexpr (EPI == EPI_F32) {
                    Cf[(size_t)row * Nn + col] = v;
                } else if constexpr (EPI == EPI_SIG) {
                    v += bias[col];
                    v = 1.f / (1.f + __expf(-v));
                    Cb[cb_off + (size_t)row * Nn + col] = v;
                } else {   // EPI_SP
                    v += bias[col];
                    float sp = (v > 20.f) ? v : log1pf(__expf(v));
                    sp = fminf(fmaxf(sp, 1e-4f), 1e4f);
                    Cb[cb_off + (size_t)row * Nn + col] = sp;
                }
            }
        }
    }
}

// ---------------------------------------------------------------------------
// Tiled VALU GEMM — small GEMMs only (K or Nn = 64..256), both modes.
// A is always fp32 workspace; B/bias in mode dtype.
// ---------------------------------------------------------------------------
template <int EPI>
__global__ __launch_bounds__(256) void gemm_tiled(
    const float* __restrict__ A, const void* __restrict__ B,
    const void* __restrict__ bias,
    float* __restrict__ Cf, void* __restrict__ Cb, size_t cb_off,
    int M, int K, int Nn, const int* __restrict__ flag)
{
    __shared__ __align__(16) float As[16][68];
    __shared__ __align__(16) float Bs[16][68];

    const int bf = *flag;
    const int t = threadIdx.x;
    const int bm0 = blockIdx.x * 64, bn0 = blockIdx.y * 64;
    const int tx = t & 15, ty = t >> 4;

    const int am = t >> 2;
    const int ak = (t & 3) * 4;
    const int gm = bm0 + am;
    const bool arow = gm < M;
    const int bk = t >> 4;
    const int bn = (t & 15) * 4;
    const bool bcol = (bn0 + bn + 3) < Nn;

    float acc[4][4] = {};

    for (int k0 = 0; k0 < K; k0 += 16) {
        float av0 = 0.f, av1 = 0.f, av2 = 0.f, av3 = 0.f;
        float bv0 = 0.f, bv1 = 0.f, bv2 = 0.f, bv3 = 0.f;
        if (arow) {
            size_t off = (size_t)gm * K + k0 + ak;
            float4 v = *(const float4*)(A + off);
            av0 = v.x; av1 = v.y; av2 = v.z; av3 = v.w;
        }
        if (bcol) {
            size_t off = (size_t)(k0 + bk) * Nn + bn0 + bn;
            if (bf) {
                ushort4 v = *(const ushort4*)((const bfu*)B + off);
                bv0 = b2f(v.x); bv1 = b2f(v.y); bv2 = b2f(v.z); bv3 = b2f(v.w);
            } else {
                float4 v = *(const float4*)((const float*)B + off);
                bv0 = v.x; bv1 = v.y; bv2 = v.z; bv3 = v.w;
            }
        }

        __syncthreads();
        As[ak + 0][am] = av0; As[ak + 1][am] = av1;
        As[ak + 2][am] = av2; As[ak + 3][am] = av3;
        *(float4*)&Bs[bk][bn] = make_float4(bv0, bv1, bv2, bv3);
        __syncthreads();

        #pragma unroll
        for (int k = 0; k < 16; k++) {
            float4 a4 = *(const float4*)&As[k][ty * 4];
            float4 b4 = *(const float4*)&Bs[k][tx * 4];
            float aa[4] = {a4.x, a4.y, a4.z, a4.w};
            float bb[4] = {b4.x, b4.y, b4.z, b4.w};
            #pragma unroll
            for (int i = 0; i < 4; i++)
                #pragma unroll
                for (int j = 0; j < 4; j++)
                    acc[i][j] += aa[i] * bb[j];
        }
    }

    #pragma unroll
    for (int i = 0; i < 4; i++) {
        int row = bm0 + ty * 4 + i;
        if (row >= M) continue;
        #pragma unroll
        for (int j = 0; j < 4; j++) {
            int col = bn0 + tx * 4 + j;
            if (col >= Nn) continue;
            float v = acc[i][j];
            if constexpr (EPI == EPI_F32) {
                Cf[(size_t)row * Nn + col] = v;
            } else if constexpr (EPI == EPI_SIG) {
                v += ldm(bias, col, bf);
                v = 1.f / (1.f + __expf(-v));
                stm(Cb, cb_off + (size_t)row * Nn + col, v, bf);
            } else {
                v += ldm(bias, col, bf);
                float sp = (v > 20.f) ? v : log1pf(__expf(v));
                sp = fminf(fmaxf(sp, 1e-4f), 1e4f);
                stm(Cb, cb_off + (size_t)row * Nn + col, sp, bf);
            }
        }
    }
}

// out[dst] += w * Hin[src]  (one wave per edge; lanes stride columns)
__global__ __launch_bounds__(256) void spmm_scatter(
    const float* __restrict__ Hin, const int* __restrict__ src,
    const int* __restrict__ dst, const void* __restrict__ w,
    float* __restrict__ outp, int E, int C, const int* __restrict__ flag)
{
    int bf = *flag;
    int gw = (blockIdx.x * 256 + threadIdx.x) >> 6;
    int lane = threadIdx.x & 63;
    if (gw >= E) return;
    int s = src[gw], d = dst[gw];
    float ww = ldm(w, gw, bf);
    const float* hp = Hin + (size_t)s * C;
    float* op = outp + (size_t)d * C;
    for (int c = lane; c < C; c += 64)
        atomicAdd(&op[c], ww * hp[c]);
}

// H = relu(H + bias[c]),  C power of two
__global__ __launch_bounds__(256) void bias_relu_k(
    float* __restrict__ H, const void* __restrict__ bias, int total, int Cm1,
    const int* __restrict__ flag)
{
    int bf = *flag;
    int i = blockIdx.x * 256 + threadIdx.x;
    if (i >= total) return;
    float v = H[i] + ldm(bias, i & Cm1, bf);
    H[i] = fmaxf(v, 0.f);
}

// E += bias[c] (C=64); keep fp32 copy, also emit output at out_off
__global__ __launch_bounds__(256) void bias_store_emb_k(
    float* __restrict__ Ef, const void* __restrict__ bias,
    void* __restrict__ outb, size_t out_off, int total,
    const int* __restrict__ flag)
{
    int bf = *flag;
    int i = blockIdx.x * 256 + threadIdx.x;
    if (i >= total) return;
    float v = Ef[i] + ldm(bias, i & 63, bf);
    Ef[i] = v;
    stm(outb, out_off + i, v, bf);
}

// BatchNorm1d (eval) + bias + relu on [N,256] fp32, in-place.
// Emits bf16 hi (both modes; in bf16 mode this IS the MFMA A operand) and,
// in fp32 mode, the bf16 lo residual (split-MFMA decoder A operand).
__global__ __launch_bounds__(256) void bn_relu_k(
    float* __restrict__ H, const void* __restrict__ bd,
    const void* __restrict__ g, const void* __restrict__ b,
    const void* __restrict__ rm, const void* __restrict__ rv,
    bfu* __restrict__ hb, bfu* __restrict__ lb, int total,
    const int* __restrict__ flag)
{
    int bf = *flag;
    int i = blockIdx.x * 256 + threadIdx.x;
    if (i >= total) return;
    int c = i & 255;
    float v = H[i] + ldm(bd, c, bf);
    v = (v - ldm(rm, c, bf)) * rsqrtf(ldm(rv, c, bf) + 1e-5f) * ldm(g, c, bf)
        + ldm(b, c, bf);
    v = fmaxf(v, 0.f);
    H[i] = v;
    bfu h = f2b(v);
    hb[i] = h;
    if (!bf) lb[i] = f2b(v - b2f(h));
}

// Per-node: attention over {emb1, emb2} + Wm MLP. One wave per node, 4/block.
__global__ __launch_bounds__(256) void attn_mlp_k(
    const float* __restrict__ E1, const float* __restrict__ E2,
    const void* __restrict__ Wa1, const void* __restrict__ ba1,
    const void* __restrict__ Wa2,
    const void* __restrict__ Wm, const void* __restrict__ bm,
    float* __restrict__ Eout, void* __restrict__ outb, size_t out_off,
    const int* __restrict__ flag)
{
    __shared__ float sh[4][3][64];   // per-wave: e1, e2, comb
    int bf = *flag;
    int wid = threadIdx.x >> 6, lane = threadIdx.x & 63;
    int node = blockIdx.x * 4 + wid;             // grid*4 == N exactly

    float e1 = E1[(size_t)node * 64 + lane];
    float e2 = E2[(size_t)node * 64 + lane];
    sh[wid][0][lane] = e1;
    sh[wid][1][lane] = e2;
    __syncthreads();

    float part = 0.f;
    if (lane < 32) {                 // lanes 0..15: logit1 partials, 16..31: logit2
        int tt = lane & 15;
        const float* es = sh[wid][lane >> 4];
        float a = 0.f;
        for (int m = 0; m < 64; m++) a += es[m] * ldm(Wa1, m * 16 + tt, bf);
        part = tanhf(a + ldm(ba1, tt, bf)) * ldm(Wa2, tt, bf);
    }
    part += __shfl_xor(part, 1);
    part += __shfl_xor(part, 2);
    part += __shfl_xor(part, 4);
    part += __shfl_xor(part, 8);
    float lg1 = __shfl(part, 0);
    float lg2 = __shfl(part, 16);
    float mx = fmaxf(lg1, lg2);
    float p1 = __expf(lg1 - mx), p2 = __expf(lg2 - mx);
    float inv = 1.f / (p1 + p2);
    float comb = (p1 * inv) * e1 + (p2 * inv) * e2;
    sh[wid][2][lane] = comb;
    __syncthreads();

    const float* cs = sh[wid][2];
    float acc = ldm(bm, lane, bf);
    for (int m = 0; m < 64; m++) acc += cs[m] * ldm(Wm, m * 64 + lane, bf);
    size_t idx = (size_t)node * 64 + lane;
    Eout[idx] = acc;
    stm(outb, out_off + idx, acc, bf);
}

extern "C" void kernel_launch(void* const* d_in, const int* in_sizes, int n_in,
                              void* d_out, int out_size, void* d_ws, size_t ws_size,
                              hipStream_t stream)
{
    const int N = 20000, F = 2000, H1 = 256, H2 = 64, E = 320000, FOUT = 2000;

    const void* x     = d_in[0];
    const int* s_src = (const int*)d_in[1];
    const int* s_dst = (const int*)d_in[2];
    const void* s_w   = d_in[3];
    const int* f_src = (const int*)d_in[4];
    const int* f_dst = (const int*)d_in[5];
    const void* f_w   = d_in[6];
    const void *Ws1 = d_in[7],  *bs1 = d_in[8];
    const void *Ws2 = d_in[9],  *bs2 = d_in[10];
    const void *Wf1 = d_in[11], *bf1 = d_in[12];
    const void *Wf2 = d_in[13], *bf2 = d_in[14];
    // d_in[15..18] = Wc1,bc1,Wc2,bc2 -> dead code in reference, skipped
    const void *Wa1 = d_in[19], *ba1 = d_in[20];
    const void *Wa2 = d_in[21];
    const void *Wm  = d_in[22], *bm  = d_in[23];
    const void *Wd  = d_in[24], *bd  = d_in[25];
    const void *bn_g = d_in[26], *bn_b = d_in[27];
    const void *bn_rm = d_in[28], *bn_rv = d_in[29];
    const void *Wpi = d_in[30], *bpi = d_in[31];
    const void *Wdp = d_in[32], *bdp = d_in[33];
    const void *Wmu = d_in[34], *bmu = d_in[35];

    // output element offsets (dtype-agnostic)
    const size_t o_emb1 = 0;
    const size_t o_emb2 = (size_t)N * H2;
    const size_t o_emb  = 2 * (size_t)N * H2;
    const size_t o_pi   = 3 * (size_t)N * H2;
    const size_t o_disp = o_pi + (size_t)N * FOUT;
    const size_t o_mean = o_disp + (size_t)N * FOUT;

    // workspace: [flag:256B][XW N*256][H N*256][G2 N*64][e1f N*64][e2f N*64][emf N*64]
    char* wsb = (char*)d_ws;
    int* flag = (int*)wsb;
    float* XW  = (float*)(wsb + 256);
    float* H   = XW + (size_t)N * H1;
    float* G2  = H  + (size_t)N * H1;
    float* e1f = G2 + (size_t)N * H2;
    float* e2f = e1f + (size_t)N * H2;
    float* emf = e2f + (size_t)N * H2;
    float* hdec = XW;              // reuse: XW dead after f-path spmm layer 1
    // aliases over dead fp32 regions (stream-ordered, never live-overlapping):
    bfu* Bt_hi = (bfu*)G2;             // weight^T staging hi (512000 elems, 1 MB)
    bfu* Bt_lo = Bt_hi + (size_t)F * H1;  // lo (1 MB); G2 region is 5.12 MB
    bfu* hdec_hi = (bfu*)H;            // decoder A hi (10.24 MB); H dead then
    bfu* hdec_lo = hdec_hi + (size_t)N * H1;   // lo (10.24 MB); H region 20.5 MB

    const int MB  = (N + 63) / 64;     // 313
    const int MB2 = (N + 127) / 128;   // 157

    detect_dtype_k<<<1, 256, 0, stream>>>((const unsigned*)s_w, flag);

    // ---- s-graph GCN ----
    transpose_bf16_k<<<dim3(32, 4), 256, 0, stream>>>(
        (const bfu*)Ws1, Bt_hi, F, H1, flag);
    transpose_split_f32_k<<<dim3(32, 4), 256, 0, stream>>>(
        (const float*)Ws1, Bt_hi, Bt_lo, F, H1, flag);
    gemm_mfma<EPI_F32><<<dim3(MB2, 2), 256, 0, stream>>>(
        (const bfu*)x, Bt_hi, nullptr, XW, nullptr, 0, N, F, H1, flag);
    gemm_mfma_split<EPI_F32, false><<<dim3(MB2, 2), 256, 0, stream>>>(
        (const float*)x, nullptr, nullptr, Bt_hi, Bt_lo, nullptr,
        XW, nullptr, 0, N, F, H1, flag);
    hipMemsetAsync(H, 0, (size_t)N * H1 * 4, stream);
    spmm_scatter<<<E / 4, 256, 0, stream>>>(XW, s_src, s_dst, s_w, H, E, H1, flag);
    bias_relu_k<<<(N * H1) / 256, 256, 0, stream>>>(H, bs1, N * H1, H1 - 1, flag);
    gemm_tiled<EPI_F32><<<dim3(MB, 1), 256, 0, stream>>>(
        H, Ws2, nullptr, G2, nullptr, 0, N, H1, H2, flag);
    hipMemsetAsync(e1f, 0, (size_t)N * H2 * 4, stream);
    spmm_scatter<<<E / 4, 256, 0, stream>>>(G2, s_src, s_dst, s_w, e1f, E, H2, flag);
    bias_store_emb_k<<<(N * H2) / 256, 256, 0, stream>>>(
        e1f, bs2, d_out, o_emb1, N * H2, flag);

    // ---- f-graph GCN (reuses XW, H, G2) ----
    transpose_bf16_k<<<dim3(32, 4), 256, 0, stream>>>(
        (const bfu*)Wf1, Bt_hi, F, H1, flag);
    transpose_split_f32_k<<<dim3(32, 4), 256, 0, stream>>>(
        (const float*)Wf1, Bt_hi, Bt_lo, F, H1, flag);
    gemm_mfma<EPI_F32><<<dim3(MB2, 2), 256, 0, stream>>>(
        (const bfu*)x, Bt_hi, nullptr, XW, nullptr, 0, N, F, H1, flag);
    gemm_mfma_split<EPI_F32, false><<<dim3(MB2, 2), 256, 0, stream>>>(
        (const float*)x, nullptr, nullptr, Bt_hi, Bt_lo, nullptr,
        XW, nullptr, 0, N, F, H1, flag);
    hipMemsetAsync(H, 0, (size_t)N * H1 * 4, stream);
    spmm_scatter<<<E / 4, 256, 0, stream>>>(XW, f_src, f_dst, f_w, H, E, H1, flag);
    bias_relu_k<<<(N * H1) / 256, 256, 0, stream>>>(H, bf1, N * H1, H1 - 1, flag);
    gemm_tiled<EPI_F32><<<dim3(MB, 1), 256, 0, stream>>>(
        H, Wf2, nullptr, G2, nullptr, 0, N, H1, H2, flag);
    hipMemsetAsync(e2f, 0, (size_t)N * H2 * 4, stream);
    spmm_scatter<<<E / 4, 256, 0, stream>>>(G2, f_src, f_dst, f_w, e2f, E, H2, flag);
    bias_store_emb_k<<<(N * H2) / 256, 256, 0, stream>>>(
        e2f, bf2, d_out, o_emb2, N * H2, flag);

    // ---- attention + Wm ----
    attn_mlp_k<<<N / 4, 256, 0, stream>>>(
        e1f, e2f, Wa1, ba1, Wa2, Wm, bm, emf, d_out, o_emb, flag);

    // ---- decoder ----
    gemm_tiled<EPI_F32><<<dim3(MB, 4), 256, 0, stream>>>(
        emf, Wd, nullptr, hdec, nullptr, 0, N, H2, H1, flag);
    bn_relu_k<<<(N * H1) / 256, 256, 0, stream>>>(
        hdec, bd, bn_g, bn_b, bn_rm, bn_rv, hdec_hi, hdec_lo, N * H1, flag);

    // pi
    transpose_bf16_k<<<dim3(4, 32), 256, 0, stream>>>(
        (const bfu*)Wpi, Bt_hi, H1, FOUT, flag);
    transpose_split_f32_k<<<dim3(4, 32), 256, 0, stream>>>(
        (const float*)Wpi, Bt_hi, Bt_lo, H1, FOUT, flag);
    gemm_mfma<EPI_SIG><<<dim3(MB2, 16), 256, 0, stream>>>(
        hdec_hi, Bt_hi, bpi, nullptr, d_out, o_pi, N, H1, FOUT, flag);
    gemm_mfma_split<EPI_SIG, true><<<dim3(MB2, 16), 256, 0, stream>>>(
        nullptr, hdec_hi, hdec_lo, Bt_hi, Bt_lo, (const float*)bpi,
        nullptr, (float*)d_out, o_pi, N, H1, FOUT, flag);
    // disp
    transpose_bf16_k<<<dim3(4, 32), 256, 0, stream>>>(
        (const bfu*)Wdp, Bt_hi, H1, FOUT, flag);
    transpose_split_f32_k<<<dim3(4, 32), 256, 0, stream>>>(
        (const float*)Wdp, Bt_hi, Bt_lo, H1, FOUT, flag);
    gemm_mfma<EPI_SP><<<dim3(MB2, 16), 256, 0, stream>>>(
        hdec_hi, Bt_hi, bdp, nullptr, d_out, o_disp, N, H1, FOUT, flag);
    gemm_mfma_split<EPI_SP, true><<<dim3(MB2, 16), 256, 0, stream>>>(
        nullptr, hdec_hi, hdec_lo, Bt_hi, Bt_lo, (const float*)bdp,
        nullptr, (float*)d_out, o_disp, N, H1, FOUT, flag);
    // mean
    transpose_bf16_k<<<dim3(4, 32), 256, 0, stream>>>(
        (const bfu*)Wmu, Bt_hi, H1, FOUT, flag);
    transpose_split_f32_k<<<dim3(4, 32), 256, 0, stream>>>(
        (const float*)Wmu, Bt_hi, Bt_lo, H1, FOUT, flag);
    gemm_mfma<EPI_SIG><<<dim3(MB2, 16), 256, 0, stream>>>(
        hdec_hi, Bt_hi, bmu, nullptr, d_out, o_mean, N, H1, FOUT, flag);
    gemm_mfma_split<EPI_SIG, true><<<dim3(MB2, 16), 256, 0, stream>>>(
        nullptr, hdec_hi, hdec_lo, Bt_hi, Bt_lo, (const float*)bmu,
        nullptr, (float*)d_out, o_mean, N, H1, FOUT, flag);
}